// Round 1
// baseline (720.749 us; speedup 1.0000x reference)
//
#include <hip/hip_runtime.h>
#include <stdint.h>

#define PRIME 2147483647LL
#define NUM_EMB 100000
#define NUM_BUCKETS 65536
#define EMB 64
#define N_ARY 32
#define NDIG 16

struct HashConsts {
  long long seqA[NDIG];
  long long hashA[2];
  long long hashB[2];
};

__global__ __launch_bounds__(256) void hash_logits_kernel(
    const int* __restrict__ seq,    // [B,16] int32
    const float* __restrict__ rep,  // [B,16,64]
    const float* __restrict__ iw,   // [NUM_EMB,2]
    const float* __restrict__ bt,   // [NUM_BUCKETS, 2048]
    float* __restrict__ out,        // [B,16,32]
    HashConsts hc)
{
  const int bid  = blockIdx.x;
  const int b    = bid >> 2;
  const int wave = threadIdx.x >> 6;
  const int d    = ((bid & 3) << 2) | wave;   // 0..15
  const int lane = threadIdx.x & 63;
  const int g    = lane >> 4;                 // 0..3 (output a-group)
  const int sub  = lane & 15;                 // 0..15 (e-fragment)

  // ---- per-(b,d) prefix-hash id (uniform across the wave, cheap) ----
  const int* srow = seq + b * NDIG;
  int v[NDIG];
  int len = 0;
#pragma unroll
  for (int j = 0; j < NDIG; ++j) { v[j] = srow[j]; len += (v[j] != 0); }
  int idx = min(d, max(len - 1, 0));
  long long acc = 0;
#pragma unroll
  for (int j = 0; j < NDIG; ++j) {
    if (j <= idx) acc += hc.seqA[j] * (long long)v[j];
  }
  const long long id = acc % PRIME;

  const int widx = (int)(id % NUM_EMB);
  const float w0 = iw[widx * 2 + 0];
  const float w1 = iw[widx * 2 + 1];
  const unsigned int bk0 =
      (unsigned int)((hc.hashA[0] * id + hc.hashB[0]) % PRIME) & (NUM_BUCKETS - 1);
  const unsigned int bk1 =
      (unsigned int)((hc.hashA[1] * id + hc.hashB[1]) % PRIME) & (NUM_BUCKETS - 1);

  // ---- main loop: combine two bucket rows, dot with rep ----
  const float4* row0 = (const float4*)(bt + (size_t)bk0 * (N_ARY * EMB));
  const float4* row1 = (const float4*)(bt + (size_t)bk1 * (N_ARY * EMB));
  const float4 r = *(const float4*)(rep + ((size_t)b * NDIG + d) * EMB + sub * 4);

  float s[8];
#pragma unroll
  for (int k = 0; k < 8; ++k) {
    // lane reads elements [4*lane + 256k .. +3] of each row: fully coalesced 1KB/wave/instr
    float4 v0 = row0[lane + 64 * k];
    float4 v1 = row1[lane + 64 * k];
    float ex = w0 * v0.x + w1 * v1.x;
    float ey = w0 * v0.y + w1 * v1.y;
    float ez = w0 * v0.z + w1 * v1.z;
    float ew = w0 * v0.w + w1 * v1.w;
    // this lane's elements belong to a = g + 4k, e = sub*4 .. sub*4+3
    s[k] = ex * r.x + ey * r.y + ez * r.z + ew * r.w;
  }
  // reduce over the 16-lane subgroup (sub bits 0..3); g bits untouched
#pragma unroll
  for (int m = 1; m <= 8; m <<= 1) {
#pragma unroll
    for (int k = 0; k < 8; ++k) s[k] += __shfl_xor(s[k], m, 64);
  }
  if (sub == 0) {
    float* obase = out + ((size_t)b * NDIG + d) * N_ARY + g;
#pragma unroll
    for (int k = 0; k < 8; ++k) obase[4 * k] = s[k];  // a = g + 4k
  }
}

extern "C" void kernel_launch(void* const* d_in, const int* in_sizes, int n_in,
                              void* d_out, int out_size, void* d_ws, size_t ws_size,
                              hipStream_t stream) {
  // ---- reproduce np.random.RandomState(42) module-level constants on host ----
  // MT19937 with numpy legacy seeding + legacy masked-rejection bounded ints.
  // Range < 2^32 -> one 32-bit draw per sample (randomkit/distributions.c 32-bit path).
  uint32_t mt[624];
  int mti;
  mt[0] = 42u;
  for (int i = 1; i < 624; ++i)
    mt[i] = 1812433253u * (mt[i - 1] ^ (mt[i - 1] >> 30)) + (uint32_t)i;
  mti = 624;
  auto next32 = [&]() -> uint32_t {
    if (mti >= 624) {
      for (int i = 0; i < 624; ++i) {
        uint32_t y = (mt[i] & 0x80000000u) | (mt[(i + 1) % 624] & 0x7fffffffu);
        uint32_t x = mt[(i + 397) % 624] ^ (y >> 1);
        if (y & 1u) x ^= 2567483615u;
        mt[i] = x;
      }
      mti = 0;
    }
    uint32_t y = mt[mti++];
    y ^= y >> 11;
    y ^= (y << 7) & 2636928640u;
    y ^= (y << 15) & 4022730752u;
    y ^= y >> 18;
    return y;
  };
  auto draw = [&](uint32_t rng_incl) -> uint32_t {  // mask = 0x7FFFFFFF for our ranges
    uint32_t val;
    do { val = next32() & 0x7FFFFFFFu; } while (val > rng_incl);
    return val;
  };
  HashConsts hc;
  for (int i = 0; i < NDIG; ++i) hc.seqA[i] = 1LL + (long long)draw(2147483645u);  // randint(1,PRIME)
  for (int i = 0; i < 2; ++i)    hc.hashA[i] = 1LL + (long long)draw(2147483645u); // randint(1,PRIME)
  for (int i = 0; i < 2; ++i)    hc.hashB[i] = (long long)draw(2147483646u);       // randint(0,PRIME)

  const int*   seq = (const int*)d_in[0];
  const float* rep = (const float*)d_in[1];
  const float* iw  = (const float*)d_in[2];
  const float* bt  = (const float*)d_in[3];
  float*       out = (float*)d_out;

  const int B = in_sizes[0] / NDIG;  // 4096
  dim3 grid(B * 4), block(256);
  hipLaunchKernelGGL(hash_logits_kernel, grid, block, 0, stream,
                     seq, rep, iw, bt, out, hc);
}